// Round 7
// baseline (1007.355 us; speedup 1.0000x reference)
//
#include <hip/hip_runtime.h>
#include <hip/hip_bf16.h>

#define N_NODES 32768
#define F_IN    32
#define HC      64
#define HEADS   4
#define NE      524288
#define NET     (NE + N_NODES)   /* 557056 = 2176*256 */
#define NG      64
#define TT      512
#define OUTF    24

__device__ __forceinline__ float lrelu(float x){ return x > 0.f ? x : 0.2f*x; }
__device__ __forceinline__ float eluf (float x){ return x > 0.f ? x : __expf(x)-1.f; }
__device__ __forceinline__ float sigmf(float x){ return 1.f/(1.f+__expf(-x)); }
__device__ __forceinline__ float tanhfast(float x){ return 1.f - 2.f/(__expf(2.f*x)+1.f); }
__device__ __forceinline__ float bcast(float v, int k){
  return __int_as_float(__builtin_amdgcn_readlane(__float_as_int(v), k));
}

// ---------------- CSR build: incoming-edge lists per destination ----------------
__global__ __launch_bounds__(256) void k_deg(const int* __restrict__ ei,
                                             int* __restrict__ deg){
  int e = blockIdx.x*256 + threadIdx.x;   // e < NET
  int d = (e < NE) ? ei[NE+e] : (e - NE);
  atomicAdd(deg + d, 1);
}

__global__ __launch_bounds__(1024) void k_scan(const int* __restrict__ deg,
                                               int* __restrict__ rowptr){
  __shared__ int ps[1024];
  const int t = threadIdx.x;
  const int base = t*32;
  int local[32]; int s = 0;
  #pragma unroll
  for(int i=0;i<32;i++){ local[i]=deg[base+i]; s+=local[i]; }
  ps[t]=s; __syncthreads();
  for(int off=1; off<1024; off<<=1){
    int v = (t>=off) ? ps[t-off] : 0;
    __syncthreads();
    ps[t]+=v;
    __syncthreads();
  }
  int run = (t==0) ? 0 : ps[t-1];
  #pragma unroll
  for(int i=0;i<32;i++){ rowptr[base+i]=run; run+=local[i]; }
  if(t==1023) rowptr[N_NODES]=run;
}

__global__ __launch_bounds__(256) void k_fill(const int* __restrict__ ei,
                                              const int* __restrict__ rowptr,
                                              int* __restrict__ cur,
                                              int* __restrict__ col){
  int e = blockIdx.x*256 + threadIdx.x;   // e < NET
  int s, d;
  if(e < NE){ s = ei[e]; d = ei[NE+e]; } else { s = e-NE; d = s; }
  int pos = atomicAdd(cur + d, 1);
  col[rowptr[d] + pos] = s;
}

// ---------------- GAT layer 1, restructured (h1 never materialized) ----------------
__global__ __launch_bounds__(256) void k_alpha1x(const float* __restrict__ x,
                                                 const float* __restrict__ W1,
                                                 const float* __restrict__ a_src,
                                                 const float* __restrict__ a_dst,
                                                 float* __restrict__ as1,
                                                 float* __restrict__ ad1){
  __shared__ float ps[256];
  const int tid = threadIdx.x;
  {
    const int k = tid>>3, q = tid&7;
    const int h = q>>1, isd = q&1;
    const float* av = (isd ? a_dst : a_src) + h*64;
    const float* wr = W1 + k*256 + h*64;
    float acc = 0.f;
    #pragma unroll
    for(int c=0;c<64;c++) acc += wr[c]*av[c];
    ps[(isd?128:0) + k*4 + h] = acc;
  }
  __syncthreads();
  const int n = blockIdx.x*256 + tid;
  const float4* xr = (const float4*)(x + n*32);
  float sa0=0.f,sa1=0.f,sa2=0.f,sa3=0.f, sd0=0.f,sd1=0.f,sd2=0.f,sd3=0.f;
  #pragma unroll
  for(int k4=0;k4<8;k4++){
    float4 v = xr[k4];
    const float* pa = ps + (4*k4)*4;
    const float* pd = ps + 128 + (4*k4)*4;
    sa0 += v.x*pa[0] + v.y*pa[4] + v.z*pa[8]  + v.w*pa[12];
    sa1 += v.x*pa[1] + v.y*pa[5] + v.z*pa[9]  + v.w*pa[13];
    sa2 += v.x*pa[2] + v.y*pa[6] + v.z*pa[10] + v.w*pa[14];
    sa3 += v.x*pa[3] + v.y*pa[7] + v.z*pa[11] + v.w*pa[15];
    sd0 += v.x*pd[0] + v.y*pd[4] + v.z*pd[8]  + v.w*pd[12];
    sd1 += v.x*pd[1] + v.y*pd[5] + v.z*pd[9]  + v.w*pd[13];
    sd2 += v.x*pd[2] + v.y*pd[6] + v.z*pd[10] + v.w*pd[14];
    sd3 += v.x*pd[3] + v.y*pd[7] + v.z*pd[11] + v.w*pd[15];
  }
  *(float4*)(as1+n*4) = make_float4(sa0,sa1,sa2,sa3);
  *(float4*)(ad1+n*4) = make_float4(sd0,sd1,sd2,sd3);
}

// aggregate x per (node, head): agg[d,h,k] = sum_e w_e^h x[src_e,k]; s14 = sum w.
__global__ __launch_bounds__(256) void k_gatx(const int* __restrict__ rowptr,
                                              const int* __restrict__ col,
                                              const float* __restrict__ as1,
                                              const float* __restrict__ ad1,
                                              const float* __restrict__ x,
                                              float* __restrict__ agg,
                                              float* __restrict__ s14){
  const int node = blockIdx.x*4 + (threadIdx.x>>6);
  const int lane = threadIdx.x & 63;
  const int h0   = lane>>5;                  // 0 or 1
  const int c    = lane & 31;
  const int beg = rowptr[node], end = rowptr[node+1];
  const float adA = ad1[node*4 + h0];
  const float adB = ad1[node*4 + h0 + 2];
  float accA=0.f, accB=0.f, wsA=0.f, wsB=0.f;
  int j = beg;
  for(; j+3 < end; j += 4){
    int s0 = col[j], s1 = col[j+1], s2 = col[j+2], s3 = col[j+3];
    float4 q0 = *(const float4*)(as1 + s0*4);
    float4 q1 = *(const float4*)(as1 + s1*4);
    float4 q2 = *(const float4*)(as1 + s2*4);
    float4 q3 = *(const float4*)(as1 + s3*4);
    float x0 = x[s0*32 + c];
    float x1 = x[s1*32 + c];
    float x2 = x[s2*32 + c];
    float x3 = x[s3*32 + c];
    float wA0 = __expf(lrelu((h0?q0.y:q0.x) + adA));
    float wA1 = __expf(lrelu((h0?q1.y:q1.x) + adA));
    float wA2 = __expf(lrelu((h0?q2.y:q2.x) + adA));
    float wA3 = __expf(lrelu((h0?q3.y:q3.x) + adA));
    float wB0 = __expf(lrelu((h0?q0.w:q0.z) + adB));
    float wB1 = __expf(lrelu((h0?q1.w:q1.z) + adB));
    float wB2 = __expf(lrelu((h0?q2.w:q2.z) + adB));
    float wB3 = __expf(lrelu((h0?q3.w:q3.z) + adB));
    accA += wA0*x0 + wA1*x1 + wA2*x2 + wA3*x3;
    accB += wB0*x0 + wB1*x1 + wB2*x2 + wB3*x3;
    wsA  += (wA0+wA1) + (wA2+wA3);
    wsB  += (wB0+wB1) + (wB2+wB3);
  }
  for(; j < end; j++){
    int s0 = col[j];
    float4 q0 = *(const float4*)(as1 + s0*4);
    float wA0 = __expf(lrelu((h0?q0.y:q0.x) + adA));
    float wB0 = __expf(lrelu((h0?q0.w:q0.z) + adB));
    float x0 = x[s0*32 + c];
    accA += wA0*x0; accB += wB0*x0;
    wsA += wA0; wsB += wB0;
  }
  agg[node*128 + h0*32 + c]     = accA;
  agg[node*128 + (h0+2)*32 + c] = accB;
  if(c == 0){
    s14[node*4 + h0]     = wsA;
    s14[node*4 + h0 + 2] = wsB;
  }
}

// Fused: out1 = ELU(agg@W1/s + b1) [LDS only] ; h2 = out1@W2 ; as2/ad2 from h2.
__global__ __launch_bounds__(256) void k_g12(const float* __restrict__ agg,
                                             const float* __restrict__ W1,
                                             const float* __restrict__ s14,
                                             const float* __restrict__ b1,
                                             const float* __restrict__ W2,
                                             const float* __restrict__ a_src2,
                                             const float* __restrict__ a_dst2,
                                             float* __restrict__ h2,
                                             float* __restrict__ as2,
                                             float* __restrict__ ad2){
  __shared__ __align__(16) float ags[32*128];   // 16KB; reused as h2 tile
  __shared__ __align__(16) float o1s[32*256];   // 32KB
  __shared__ float sv[128];
  const int tid  = threadIdx.x;
  const int row0 = blockIdx.x*32;
  const float4* ag = (const float4*)(agg + (size_t)row0*128);
  float4* a4 = (float4*)ags;
  for(int i=tid;i<1024;i+=256) a4[i]=ag[i];
  if(tid<32) ((float4*)sv)[tid]=((const float4*)(s14+row0*4))[tid];
  float wc[32];
  #pragma unroll
  for(int k=0;k<32;k++) wc[k]=W1[k*256+tid];
  const float bb=b1[tid];
  __syncthreads();
  const int h = tid>>6;
  for(int r=0;r<32;r++){
    const float4* ar=(const float4*)(ags + r*128 + h*32);
    float acc=0.f;
    #pragma unroll
    for(int k4=0;k4<8;k4++){
      float4 v=ar[k4];
      acc += v.x*wc[4*k4]+v.y*wc[4*k4+1]+v.z*wc[4*k4+2]+v.w*wc[4*k4+3];
    }
    float inv = 1.f/(sv[r*4+h] + 1e-16f);
    o1s[r*256+tid] = eluf(acc*inv + bb);
  }
  __syncthreads();
  const int c0=(tid&15)*4;
  const int r0=(tid>>4)*2;
  float acc2[2][4]={};
  for(int k=0;k<256;k+=4){
    float wv[4][4];
    #pragma unroll
    for(int i=0;i<4;i++){
      float4 w=*(const float4*)(W2+(k+i)*64+c0);
      wv[i][0]=w.x; wv[i][1]=w.y; wv[i][2]=w.z; wv[i][3]=w.w;
    }
    #pragma unroll
    for(int i=0;i<2;i++){
      float4 xv=*(const float4*)(o1s+(r0+i)*256+k);
      #pragma unroll
      for(int j=0;j<4;j++)
        acc2[i][j]+=xv.x*wv[0][j]+xv.y*wv[1][j]+xv.z*wv[2][j]+xv.w*wv[3][j];
    }
  }
  float* h2s = ags;
  #pragma unroll
  for(int i=0;i<2;i++){
    float4 o = make_float4(acc2[i][0],acc2[i][1],acc2[i][2],acc2[i][3]);
    *(float4*)(h2 + (size_t)(row0+r0+i)*64 + c0) = o;
    *(float4*)(h2s + (r0+i)*64 + c0) = o;
  }
  __syncthreads();
  if(tid < 32){
    const float4* hp=(const float4*)(h2s + tid*64);
    float sa=0.f, sd=0.f;
    #pragma unroll
    for(int i=0;i<16;i++){
      float4 v=hp[i];
      float4 a=((const float4*)a_src2)[i];
      float4 d=((const float4*)a_dst2)[i];
      sa+=v.x*a.x+v.y*a.y+v.z*a.z+v.w*a.w;
      sd+=v.x*d.x+v.y*d.y+v.z*d.z+v.w*d.w;
    }
    as2[row0+tid]=sa; ad2[row0+tid]=sd;
  }
}

// fused gather layer 2: one wave per node, lane = channel; 4-wide unrolled.
__global__ __launch_bounds__(256) void k_gat2(const int* __restrict__ rowptr,
                                              const int* __restrict__ col,
                                              const float* __restrict__ as2,
                                              const float* __restrict__ ad2,
                                              const float* __restrict__ h2,
                                              const float* __restrict__ b2,
                                              float* __restrict__ out2){
  const int node = blockIdx.x*4 + (threadIdx.x>>6);
  const int lane = threadIdx.x & 63;
  const int beg = rowptr[node], end = rowptr[node+1];
  const float ad = ad2[node];
  float acc = 0.f, s = 0.f;
  int j = beg;
  for(; j+3 < end; j += 4){
    int s0 = col[j], s1 = col[j+1], s2 = col[j+2], s3 = col[j+3];
    float a0 = as2[s0], a1 = as2[s1], a2 = as2[s2], a3 = as2[s3];
    float v0 = h2[s0*64+lane], v1 = h2[s1*64+lane];
    float v2 = h2[s2*64+lane], v3 = h2[s3*64+lane];
    float w0 = __expf(lrelu(a0 + ad));
    float w1 = __expf(lrelu(a1 + ad));
    float w2 = __expf(lrelu(a2 + ad));
    float w3 = __expf(lrelu(a3 + ad));
    acc += w0*v0 + w1*v1 + w2*v2 + w3*v3;
    s += (w0+w1) + (w2+w3);
  }
  for(; j < end; j++){
    int s0 = col[j];
    float w0 = __expf(lrelu(as2[s0] + ad));
    acc += w0*h2[s0*64+lane];
    s += w0;
  }
  const float inv = 1.f/(s + 1e-16f);
  out2[node*64+lane] = eluf(acc*inv + b2[lane]);
}

// ---------------- GRU input GEMM: gi = in @ Wih^T + bih (+bhh for r,z cols) ----
// bhh_r/bhh_z fold into gi exactly; bhh_n stays in the GRU kernel (c0 init).
__global__ __launch_bounds__(256) void k_gemm_gi(const float* __restrict__ in,
                                                 const float* __restrict__ Wih,
                                                 const float* __restrict__ bih,
                                                 const float* __restrict__ bhh,
                                                 float* __restrict__ gi){
  __shared__ __align__(16) float xs[64*64];
  __shared__ float wT[64*192];
  const int tid=threadIdx.x;
  const int row0=blockIdx.x*64;
  const float4* xg=(const float4*)(in+row0*64);
  float4* xs4=(float4*)xs;
  for(int i=tid;i<1024;i+=256) xs4[i]=xg[i];
  for(int i=tid;i<12288;i+=256){ wT[(i&63)*192+(i>>6)] = Wih[i]; }
  __syncthreads();
  if(tid<192){
    float wr[64];
    #pragma unroll
    for(int k=0;k<64;k++) wr[k]=wT[k*192+tid];
    const float bj = bih[tid] + (tid < 128 ? bhh[tid] : 0.f);
    for(int r=0;r<64;r++){
      float acc=bj;
      const float4* xr=(const float4*)(xs+r*64);
      #pragma unroll
      for(int k4=0;k4<16;k4++){
        float4 v=xr[k4];
        acc+=v.x*wr[4*k4]+v.y*wr[4*k4+1]+v.z*wr[4*k4+2]+v.w*wr[4*k4+3];
      }
      gi[(row0+r)*192+tid]=acc;
    }
  }
}

// ---------------- Single-wave, barrier-free GRU layer pass, W in LDS ----------
// Round-6 diagnosis (counter-backed): VALUBusy=5.3% of 6.25% ceiling = the one
// active SIMD issues 85% of cycles -> ISSUE-BOUND, ~630 VALU instr/step vs 280
// in source. The bloat is AGPR traffic: VGPR_Count=108 < 192 live W floats ->
// W homed in AGPRs (unified file, invisible in VGPR_Count); each use pays a
// v_accvgpr_read. Fix: W lives in LDS (48KB), read per step as 48 swizzled
// conflict-free ds_read_b128. Steady-state register pressure ~80 -> allocator
// keeps everything in arch VGPRs; per-step instr ~330.
// Swizzle: quad(r,q) stored at float4-index r*16 + (q ^ (r&15)). Reads for
// rows {lane,64+lane,128+lane} share one vaddr (bA + (q^s)) with ds-immediate
// offsets 0/16384/32768. Bank distribution == contiguous pattern (conflict-free).
#define GRU_STAGE_W(W)                                        \
  for(int i=lane;i<3072;i+=64){                               \
    int rr = i>>4, qq = i&15;                                 \
    WL[(rr<<4) | (qq ^ (rr&15))] = ((const float4*)(W))[i];   \
  }

#define GRU_STEP_MATVEC()                                                     \
  float a0=0.f, b0=0.f, c0=biasC;                                             \
  {                                                                           \
    float hv = h;                                                             \
    _Pragma("unroll")                                                         \
    for(int q=0;q<16;q++){                                                    \
      const float4* p = bA + (q ^ s);                                         \
      float4 wa = p[0];                                                       \
      float4 wb = p[1024];                                                    \
      float4 wc = p[2048];                                                    \
      float t0=bcast(hv,4*q+0), t1=bcast(hv,4*q+1);                           \
      float t2=bcast(hv,4*q+2), t3=bcast(hv,4*q+3);                           \
      a0=fmaf(t0,wa.x,a0); b0=fmaf(t0,wb.x,b0); c0=fmaf(t0,wc.x,c0);          \
      a0=fmaf(t1,wa.y,a0); b0=fmaf(t1,wb.y,b0); c0=fmaf(t1,wc.y,c0);          \
      a0=fmaf(t2,wa.z,a0); b0=fmaf(t2,wb.z,b0); c0=fmaf(t2,wc.z,c0);          \
      a0=fmaf(t3,wa.w,a0); b0=fmaf(t3,wb.w,b0); c0=fmaf(t3,wc.w,c0);          \
    }                                                                         \
  }

__global__ __launch_bounds__(64,1) void k_gru_l1(const float* __restrict__ gi1,
                                                 const float* __restrict__ Whh,
                                                 const float* __restrict__ bhh,
                                                 float* __restrict__ seq){
  __shared__ __align__(16) float4 WL[3072];   // 48KB swizzled Whh
  const int lane = threadIdx.x;
  const int b    = blockIdx.x;
  const float* gib = gi1 + (size_t)b*TT*192;
  GRU_STAGE_W(Whh)
  const float biasC = bhh[128+lane];
  const int s = lane & 15;
  const float4* bA = WL + (lane<<4);
  float h = 0.f;
  float gA = gib[lane],       gB = gib[64+lane],       gC = gib[128+lane];
  float nA = gib[192+lane],   nB = gib[192+64+lane],   nC = gib[192+128+lane];
  float* sq = seq + (size_t)b*TT*64 + lane;
  __syncthreads();
  for(int t=0;t<TT;t++){
    float fA=0.f, fB=0.f, fC=0.f;
    if(t+2 < TT){
      const float* g2 = gib + (size_t)(t+2)*192;
      fA = g2[lane]; fB = g2[64+lane]; fC = g2[128+lane];
    }
    GRU_STEP_MATVEC()
    float r = sigmf(gA + a0);
    float z = sigmf(gB + b0);
    float n = tanhfast(gC + r*c0);
    h = fmaf(z, h - n, n);
    sq[(size_t)t*64] = h;
    gA = nA; gB = nB; gC = nC;
    nA = fA; nB = fB; nC = fC;
  }
}

__global__ __launch_bounds__(64,1) void k_gru_l2(const float* __restrict__ gi2,
                                                 const float* __restrict__ Whh,
                                                 const float* __restrict__ bhh,
                                                 const float* __restrict__ Wl,
                                                 const float* __restrict__ bl,
                                                 float* __restrict__ fout){
  __shared__ __align__(16) float4 WL[3072];   // 48KB swizzled Whh
  __shared__ float hf[64];
  const int lane = threadIdx.x;
  const int b    = blockIdx.x;
  const float* gib = gi2 + (size_t)b*TT*192;
  GRU_STAGE_W(Whh)
  const float biasC = bhh[128+lane];
  const int s = lane & 15;
  const float4* bA = WL + (lane<<4);
  float h = 0.f;
  float gA = gib[lane],       gB = gib[64+lane],       gC = gib[128+lane];
  float nA = gib[192+lane],   nB = gib[192+64+lane],   nC = gib[192+128+lane];
  __syncthreads();
  for(int t=0;t<TT;t++){
    float fA=0.f, fB=0.f, fC=0.f;
    if(t+2 < TT){
      const float* g2 = gib + (size_t)(t+2)*192;
      fA = g2[lane]; fB = g2[64+lane]; fC = g2[128+lane];
    }
    GRU_STEP_MATVEC()
    float r = sigmf(gA + a0);
    float z = sigmf(gB + b0);
    float n = tanhfast(gC + r*c0);
    h = fmaf(z, h - n, n);
    gA = nA; gB = nB; gC = nC;
    nA = fA; nB = fB; nC = fC;
  }
  hf[lane] = h;
  __syncthreads();
  if(lane < 24){
    float acc = bl[lane];
    const float4* wl4 = (const float4*)(Wl + lane*64);
    #pragma unroll
    for(int k4=0;k4<16;k4++){
      float4 h4 = *(const float4*)(hf + 4*k4);
      float4 w4 = wl4[k4];
      acc += h4.x*w4.x + h4.y*w4.y + h4.z*w4.z + h4.w*w4.w;
    }
    fout[b*24+lane] = acc;
  }
}

extern "C" void kernel_launch(void* const* d_in, const int* in_sizes, int n_in,
                              void* d_out, int out_size, void* d_ws, size_t ws_size,
                              hipStream_t stream){
  const float* x     =(const float*)d_in[0];
  const int*   ei    =(const int*  )d_in[1];
  const float* W1    =(const float*)d_in[3];
  const float* a_src1=(const float*)d_in[4];
  const float* a_dst1=(const float*)d_in[5];
  const float* b1    =(const float*)d_in[6];
  const float* W2    =(const float*)d_in[7];
  const float* a_src2=(const float*)d_in[8];
  const float* a_dst2=(const float*)d_in[9];
  const float* b2    =(const float*)d_in[10];
  const float* Wih0  =(const float*)d_in[11];
  const float* Whh0  =(const float*)d_in[12];
  const float* bih0  =(const float*)d_in[13];
  const float* bhh0  =(const float*)d_in[14];
  const float* Wih1  =(const float*)d_in[15];
  const float* Whh1  =(const float*)d_in[16];
  const float* bih1  =(const float*)d_in[17];
  const float* bhh1  =(const float*)d_in[18];
  const float* Wl    =(const float*)d_in[19];
  const float* bl    =(const float*)d_in[20];

  float* ws   = (float*)d_ws;
  float* agg  = ws;                  // 4194304 [N,128] (dead after k_g12)
  float* s14  = ws + 4194304;        // 131072 [N,4]
  float* gi1  = ws;                  // [N,192] overwrites agg after it's dead
  float* out2 = ws + 8388608;        // 2097152 (k_gat2 output; consumed by 1st gemm)
  float* seq  = ws + 8388608;        // [N,64] l1 output (aliases out2 -- safe: written after)
  float* gi2  = ws + 10485760;       // [N,192] 6291456 floats (ends at 16777216)
  float* h2   = ws + 16777216;       // 2097152
  float* as1  = ws + 18874368;       // 131072
  float* ad1  = as1 + 131072;        // 131072
  float* as2  = ad1 + 131072;        // 32768
  float* ad2  = as2 + 32768;         // 32768
  int* rowptr = (int*)(ad2 + 32768); // 32769 (padded to 32800)
  int* deg    = rowptr + 32800;      // 32768
  int* cur    = deg + 32768;         // 32768 (contiguous with deg: one memset)
  int* col    = cur + 32768;         // 557056
  float* fo   = (float*)d_out;

  hipMemsetAsync(deg, 0, 2*32768*sizeof(int), stream);  // deg + cur

  k_deg   <<<2176,256,0,stream>>>(ei,deg);
  k_scan  <<<1  ,1024,0,stream>>>(deg,rowptr);
  k_fill  <<<2176,256,0,stream>>>(ei,rowptr,cur,col);

  k_alpha1x<<<128 ,256,0,stream>>>(x,W1,a_src1,a_dst1,as1,ad1);
  k_gatx   <<<8192,256,0,stream>>>(rowptr,col,as1,ad1,x,agg,s14);
  k_g12    <<<1024,256,0,stream>>>(agg,W1,s14,b1,W2,a_src2,a_dst2,h2,as2,ad2);
  k_gat2   <<<8192,256,0,stream>>>(rowptr,col,as2,ad2,h2,b2,out2);
  k_gemm_gi<<<512 ,256,0,stream>>>(out2,Wih0,bih0,bhh0,gi1);
  k_gru_l1 <<<64  ,64 ,0,stream>>>(gi1,Whh0,bhh0,seq);
  k_gemm_gi<<<512 ,256,0,stream>>>(seq,Wih1,bih1,bhh1,gi2);
  k_gru_l2 <<<64  ,64 ,0,stream>>>(gi2,Whh1,bhh1,Wl,bl,fo);
  (void)in_sizes; (void)n_in; (void)out_size; (void)ws_size;
}

// Round 8
// 928.077 us; speedup vs baseline: 1.0854x; 1.0854x over previous
//
#include <hip/hip_runtime.h>
#include <hip/hip_bf16.h>

#define N_NODES 32768
#define F_IN    32
#define HC      64
#define HEADS   4
#define NE      524288
#define NET     (NE + N_NODES)   /* 557056 = 2176*256 */
#define NG      64
#define TT      512
#define OUTF    24

__device__ __forceinline__ float lrelu(float x){ return x > 0.f ? x : 0.2f*x; }
__device__ __forceinline__ float eluf (float x){ return x > 0.f ? x : __expf(x)-1.f; }
__device__ __forceinline__ float sigmf(float x){ return 1.f/(1.f+__expf(-x)); }
__device__ __forceinline__ float tanhfast(float x){ return 1.f - 2.f/(__expf(2.f*x)+1.f); }

// ---------------- CSR build: incoming-edge lists per destination ----------------
__global__ __launch_bounds__(256) void k_deg(const int* __restrict__ ei,
                                             int* __restrict__ deg){
  int e = blockIdx.x*256 + threadIdx.x;   // e < NET
  int d = (e < NE) ? ei[NE+e] : (e - NE);
  atomicAdd(deg + d, 1);
}

__global__ __launch_bounds__(1024) void k_scan(const int* __restrict__ deg,
                                               int* __restrict__ rowptr){
  __shared__ int ps[1024];
  const int t = threadIdx.x;
  const int base = t*32;
  int local[32]; int s = 0;
  #pragma unroll
  for(int i=0;i<32;i++){ local[i]=deg[base+i]; s+=local[i]; }
  ps[t]=s; __syncthreads();
  for(int off=1; off<1024; off<<=1){
    int v = (t>=off) ? ps[t-off] : 0;
    __syncthreads();
    ps[t]+=v;
    __syncthreads();
  }
  int run = (t==0) ? 0 : ps[t-1];
  #pragma unroll
  for(int i=0;i<32;i++){ rowptr[base+i]=run; run+=local[i]; }
  if(t==1023) rowptr[N_NODES]=run;
}

__global__ __launch_bounds__(256) void k_fill(const int* __restrict__ ei,
                                              const int* __restrict__ rowptr,
                                              int* __restrict__ cur,
                                              int* __restrict__ col){
  int e = blockIdx.x*256 + threadIdx.x;   // e < NET
  int s, d;
  if(e < NE){ s = ei[e]; d = ei[NE+e]; } else { s = e-NE; d = s; }
  int pos = atomicAdd(cur + d, 1);
  col[rowptr[d] + pos] = s;
}

// ---------------- GAT layer 1, restructured (h1 never materialized) ----------------
__global__ __launch_bounds__(256) void k_alpha1x(const float* __restrict__ x,
                                                 const float* __restrict__ W1,
                                                 const float* __restrict__ a_src,
                                                 const float* __restrict__ a_dst,
                                                 float* __restrict__ as1,
                                                 float* __restrict__ ad1){
  __shared__ float ps[256];
  const int tid = threadIdx.x;
  {
    const int k = tid>>3, q = tid&7;
    const int h = q>>1, isd = q&1;
    const float* av = (isd ? a_dst : a_src) + h*64;
    const float* wr = W1 + k*256 + h*64;
    float acc = 0.f;
    #pragma unroll
    for(int c=0;c<64;c++) acc += wr[c]*av[c];
    ps[(isd?128:0) + k*4 + h] = acc;
  }
  __syncthreads();
  const int n = blockIdx.x*256 + tid;
  const float4* xr = (const float4*)(x + n*32);
  float sa0=0.f,sa1=0.f,sa2=0.f,sa3=0.f, sd0=0.f,sd1=0.f,sd2=0.f,sd3=0.f;
  #pragma unroll
  for(int k4=0;k4<8;k4++){
    float4 v = xr[k4];
    const float* pa = ps + (4*k4)*4;
    const float* pd = ps + 128 + (4*k4)*4;
    sa0 += v.x*pa[0] + v.y*pa[4] + v.z*pa[8]  + v.w*pa[12];
    sa1 += v.x*pa[1] + v.y*pa[5] + v.z*pa[9]  + v.w*pa[13];
    sa2 += v.x*pa[2] + v.y*pa[6] + v.z*pa[10] + v.w*pa[14];
    sa3 += v.x*pa[3] + v.y*pa[7] + v.z*pa[11] + v.w*pa[15];
    sd0 += v.x*pd[0] + v.y*pd[4] + v.z*pd[8]  + v.w*pd[12];
    sd1 += v.x*pd[1] + v.y*pd[5] + v.z*pd[9]  + v.w*pd[13];
    sd2 += v.x*pd[2] + v.y*pd[6] + v.z*pd[10] + v.w*pd[14];
    sd3 += v.x*pd[3] + v.y*pd[7] + v.z*pd[11] + v.w*pd[15];
  }
  *(float4*)(as1+n*4) = make_float4(sa0,sa1,sa2,sa3);
  *(float4*)(ad1+n*4) = make_float4(sd0,sd1,sd2,sd3);
}

// aggregate x per (node, head): agg[d,h,k] = sum_e w_e^h x[src_e,k]; s14 = sum w.
__global__ __launch_bounds__(256) void k_gatx(const int* __restrict__ rowptr,
                                              const int* __restrict__ col,
                                              const float* __restrict__ as1,
                                              const float* __restrict__ ad1,
                                              const float* __restrict__ x,
                                              float* __restrict__ agg,
                                              float* __restrict__ s14){
  const int node = blockIdx.x*4 + (threadIdx.x>>6);
  const int lane = threadIdx.x & 63;
  const int h0   = lane>>5;                  // 0 or 1
  const int c    = lane & 31;
  const int beg = rowptr[node], end = rowptr[node+1];
  const float adA = ad1[node*4 + h0];
  const float adB = ad1[node*4 + h0 + 2];
  float accA=0.f, accB=0.f, wsA=0.f, wsB=0.f;
  int j = beg;
  for(; j+3 < end; j += 4){
    int s0 = col[j], s1 = col[j+1], s2 = col[j+2], s3 = col[j+3];
    float4 q0 = *(const float4*)(as1 + s0*4);
    float4 q1 = *(const float4*)(as1 + s1*4);
    float4 q2 = *(const float4*)(as1 + s2*4);
    float4 q3 = *(const float4*)(as1 + s3*4);
    float x0 = x[s0*32 + c];
    float x1 = x[s1*32 + c];
    float x2 = x[s2*32 + c];
    float x3 = x[s3*32 + c];
    float wA0 = __expf(lrelu((h0?q0.y:q0.x) + adA));
    float wA1 = __expf(lrelu((h0?q1.y:q1.x) + adA));
    float wA2 = __expf(lrelu((h0?q2.y:q2.x) + adA));
    float wA3 = __expf(lrelu((h0?q3.y:q3.x) + adA));
    float wB0 = __expf(lrelu((h0?q0.w:q0.z) + adB));
    float wB1 = __expf(lrelu((h0?q1.w:q1.z) + adB));
    float wB2 = __expf(lrelu((h0?q2.w:q2.z) + adB));
    float wB3 = __expf(lrelu((h0?q3.w:q3.z) + adB));
    accA += wA0*x0 + wA1*x1 + wA2*x2 + wA3*x3;
    accB += wB0*x0 + wB1*x1 + wB2*x2 + wB3*x3;
    wsA  += (wA0+wA1) + (wA2+wA3);
    wsB  += (wB0+wB1) + (wB2+wB3);
  }
  for(; j < end; j++){
    int s0 = col[j];
    float4 q0 = *(const float4*)(as1 + s0*4);
    float wA0 = __expf(lrelu((h0?q0.y:q0.x) + adA));
    float wB0 = __expf(lrelu((h0?q0.w:q0.z) + adB));
    float x0 = x[s0*32 + c];
    accA += wA0*x0; accB += wB0*x0;
    wsA += wA0; wsB += wB0;
  }
  agg[node*128 + h0*32 + c]     = accA;
  agg[node*128 + (h0+2)*32 + c] = accB;
  if(c == 0){
    s14[node*4 + h0]     = wsA;
    s14[node*4 + h0 + 2] = wsB;
  }
}

// Fused: out1 = ELU(agg@W1/s + b1) [LDS only] ; h2 = out1@W2 ; as2/ad2 from h2.
__global__ __launch_bounds__(256) void k_g12(const float* __restrict__ agg,
                                             const float* __restrict__ W1,
                                             const float* __restrict__ s14,
                                             const float* __restrict__ b1,
                                             const float* __restrict__ W2,
                                             const float* __restrict__ a_src2,
                                             const float* __restrict__ a_dst2,
                                             float* __restrict__ h2,
                                             float* __restrict__ as2,
                                             float* __restrict__ ad2){
  __shared__ __align__(16) float ags[32*128];   // 16KB; reused as h2 tile
  __shared__ __align__(16) float o1s[32*256];   // 32KB
  __shared__ float sv[128];
  const int tid  = threadIdx.x;
  const int row0 = blockIdx.x*32;
  const float4* ag = (const float4*)(agg + (size_t)row0*128);
  float4* a4 = (float4*)ags;
  for(int i=tid;i<1024;i+=256) a4[i]=ag[i];
  if(tid<32) ((float4*)sv)[tid]=((const float4*)(s14+row0*4))[tid];
  float wc[32];
  #pragma unroll
  for(int k=0;k<32;k++) wc[k]=W1[k*256+tid];
  const float bb=b1[tid];
  __syncthreads();
  const int h = tid>>6;
  for(int r=0;r<32;r++){
    const float4* ar=(const float4*)(ags + r*128 + h*32);
    float acc=0.f;
    #pragma unroll
    for(int k4=0;k4<8;k4++){
      float4 v=ar[k4];
      acc += v.x*wc[4*k4]+v.y*wc[4*k4+1]+v.z*wc[4*k4+2]+v.w*wc[4*k4+3];
    }
    float inv = 1.f/(sv[r*4+h] + 1e-16f);
    o1s[r*256+tid] = eluf(acc*inv + bb);
  }
  __syncthreads();
  const int c0=(tid&15)*4;
  const int r0=(tid>>4)*2;
  float acc2[2][4]={};
  for(int k=0;k<256;k+=4){
    float wv[4][4];
    #pragma unroll
    for(int i=0;i<4;i++){
      float4 w=*(const float4*)(W2+(k+i)*64+c0);
      wv[i][0]=w.x; wv[i][1]=w.y; wv[i][2]=w.z; wv[i][3]=w.w;
    }
    #pragma unroll
    for(int i=0;i<2;i++){
      float4 xv=*(const float4*)(o1s+(r0+i)*256+k);
      #pragma unroll
      for(int j=0;j<4;j++)
        acc2[i][j]+=xv.x*wv[0][j]+xv.y*wv[1][j]+xv.z*wv[2][j]+xv.w*wv[3][j];
    }
  }
  float* h2s = ags;
  #pragma unroll
  for(int i=0;i<2;i++){
    float4 o = make_float4(acc2[i][0],acc2[i][1],acc2[i][2],acc2[i][3]);
    *(float4*)(h2 + (size_t)(row0+r0+i)*64 + c0) = o;
    *(float4*)(h2s + (r0+i)*64 + c0) = o;
  }
  __syncthreads();
  if(tid < 32){
    const float4* hp=(const float4*)(h2s + tid*64);
    float sa=0.f, sd=0.f;
    #pragma unroll
    for(int i=0;i<16;i++){
      float4 v=hp[i];
      float4 a=((const float4*)a_src2)[i];
      float4 d=((const float4*)a_dst2)[i];
      sa+=v.x*a.x+v.y*a.y+v.z*a.z+v.w*a.w;
      sd+=v.x*d.x+v.y*d.y+v.z*d.z+v.w*d.w;
    }
    as2[row0+tid]=sa; ad2[row0+tid]=sd;
  }
}

// fused gather layer 2: one wave per node, lane = channel; 4-wide unrolled.
__global__ __launch_bounds__(256) void k_gat2(const int* __restrict__ rowptr,
                                              const int* __restrict__ col,
                                              const float* __restrict__ as2,
                                              const float* __restrict__ ad2,
                                              const float* __restrict__ h2,
                                              const float* __restrict__ b2,
                                              float* __restrict__ out2){
  const int node = blockIdx.x*4 + (threadIdx.x>>6);
  const int lane = threadIdx.x & 63;
  const int beg = rowptr[node], end = rowptr[node+1];
  const float ad = ad2[node];
  float acc = 0.f, s = 0.f;
  int j = beg;
  for(; j+3 < end; j += 4){
    int s0 = col[j], s1 = col[j+1], s2 = col[j+2], s3 = col[j+3];
    float a0 = as2[s0], a1 = as2[s1], a2 = as2[s2], a3 = as2[s3];
    float v0 = h2[s0*64+lane], v1 = h2[s1*64+lane];
    float v2 = h2[s2*64+lane], v3 = h2[s3*64+lane];
    float w0 = __expf(lrelu(a0 + ad));
    float w1 = __expf(lrelu(a1 + ad));
    float w2 = __expf(lrelu(a2 + ad));
    float w3 = __expf(lrelu(a3 + ad));
    acc += w0*v0 + w1*v1 + w2*v2 + w3*v3;
    s += (w0+w1) + (w2+w3);
  }
  for(; j < end; j++){
    int s0 = col[j];
    float w0 = __expf(lrelu(as2[s0] + ad));
    acc += w0*h2[s0*64+lane];
    s += w0;
  }
  const float inv = 1.f/(s + 1e-16f);
  out2[node*64+lane] = eluf(acc*inv + b2[lane]);
}

// ---------------- GRU input GEMM: gi1 = in @ Wih0^T + bih0 (+bhh0 for r,z) ----
// bhh0_r/bhh0_z fold into gi1 exactly; bhh0_n stays in k_gru3 (wave0 biasC).
__global__ __launch_bounds__(256) void k_gemm_gi(const float* __restrict__ in,
                                                 const float* __restrict__ Wih,
                                                 const float* __restrict__ bih,
                                                 const float* __restrict__ bhh,
                                                 float* __restrict__ gi){
  __shared__ __align__(16) float xs[64*64];
  __shared__ float wT[64*192];
  const int tid=threadIdx.x;
  const int row0=blockIdx.x*64;
  const float4* xg=(const float4*)(in+row0*64);
  float4* xs4=(float4*)xs;
  for(int i=tid;i<1024;i+=256) xs4[i]=xg[i];
  for(int i=tid;i<12288;i+=256){ wT[(i&63)*192+(i>>6)] = Wih[i]; }
  __syncthreads();
  if(tid<192){
    float wr[64];
    #pragma unroll
    for(int k=0;k<64;k++) wr[k]=wT[k*192+tid];
    const float bj = bih[tid] + (tid < 128 ? bhh[tid] : 0.f);
    for(int r=0;r<64;r++){
      float acc=bj;
      const float4* xr=(const float4*)(xs+r*64);
      #pragma unroll
      for(int k4=0;k4<16;k4++){
        float4 v=xr[k4];
        acc+=v.x*wr[4*k4]+v.y*wr[4*k4+1]+v.z*wr[4*k4+2]+v.w*wr[4*k4+3];
      }
      gi[(row0+r)*192+tid]=acc;
    }
  }
}

// Fused 2-layer GRU, 3 waves/block — the verified r0 structure (417us), with
// ONE critical-path change: the 64 v_readlane broadcasts per wave (each a
// VALU-writes-SGPR -> VALU-reads-SGPR hazard with wait states, and the values
// only available after an LDS read of h anyway) are replaced by 16 UNIFORM
// ds_read_b128 of h from LDS. Uniform address = broadcast (conflict-free),
// results land in VGPRs (no SGPR hazard), all 16 independent -> one lgkmcnt
// wait instead of 64 serial hazards. r6 counters showed the GRU wave is
// VALU-issuing only ~20% of cycles (1 wave/SIMD, zero TLP): latency-bound,
// so the win must come from shortening the per-step dependency chain.
__global__ __launch_bounds__(192,1) void k_gru3(const float* __restrict__ gi1,
                                                const float* __restrict__ Whh0,
                                                const float* __restrict__ bhh0,
                                                const float* __restrict__ Wih1,
                                                const float* __restrict__ bih1,
                                                const float* __restrict__ Whh1,
                                                const float* __restrict__ bhh1,
                                                const float* __restrict__ Wl,
                                                const float* __restrict__ bl,
                                                float* __restrict__ fout){
  __shared__ float h1s[64];
  __shared__ float h2s[64];
  __shared__ float gh1s[192];
  __shared__ float gi2s[192];
  __shared__ float gh2s[192];
  __shared__ float g1r[2][192];   // gi1 ring (parity)
  const int tid  = threadIdx.x;
  const int w    = tid >> 6;
  const int lane = tid & 63;
  const int b    = blockIdx.x;
  const float* gib = gi1 + (size_t)b*TT*192;

  const float* W  = (w==0) ? Whh0 : (w==1) ? Wih1 : Whh1;
  float* dst      = (w==0) ? gh1s : (w==1) ? gi2s : gh2s;

  const float4* pa = (const float4*)(W + lane*64);
  const float4* pb = (const float4*)(W + (64+lane)*64);
  const float4* pc = (const float4*)(W + (128+lane)*64);
  float4 Av0=pa[0],  Av1=pa[1],  Av2=pa[2],  Av3=pa[3];
  float4 Av4=pa[4],  Av5=pa[5],  Av6=pa[6],  Av7=pa[7];
  float4 Av8=pa[8],  Av9=pa[9],  AvA=pa[10], AvB=pa[11];
  float4 AvC=pa[12], AvD=pa[13], AvE=pa[14], AvF=pa[15];
  float4 Bv0=pb[0],  Bv1=pb[1],  Bv2=pb[2],  Bv3=pb[3];
  float4 Bv4=pb[4],  Bv5=pb[5],  Bv6=pb[6],  Bv7=pb[7];
  float4 Bv8=pb[8],  Bv9=pb[9],  BvA=pb[10], BvB=pb[11];
  float4 BvC=pb[12], BvD=pb[13], BvE=pb[14], BvF=pb[15];
  float4 Cv0=pc[0],  Cv1=pc[1],  Cv2=pc[2],  Cv3=pc[3];
  float4 Cv4=pc[4],  Cv5=pc[5],  Cv6=pc[6],  Cv7=pc[7];
  float4 Cv8=pc[8],  Cv9=pc[9],  CvA=pc[10], CvB=pc[11];
  float4 CvC=pc[12], CvD=pc[13], CvE=pc[14], CvF=pc[15];
  // Biases under r/z-folding: layer1 r/z live in gi1 (gemm); layer2 r/z in
  // wave1's gi2 bias; the n-gate bhh must stay inside r*(...) => C-chain init.
  float biasA, biasB, biasC;
  if(w == 0){      biasA = 0.f;                       biasB = 0.f;                             biasC = bhh0[128+lane]; }
  else if(w == 1){ biasA = bih1[lane] + bhh1[lane];   biasB = bih1[64+lane] + bhh1[64+lane];   biasC = bih1[128+lane]; }
  else {           biasA = 0.f;                       biasB = 0.f;                             biasC = bhh1[128+lane]; }

  float giv0 = 0.f, giv1 = 0.f, giv2 = 0.f;
  if(w == 0){                               // ring prefill: step 0 -> slot 0; regs = step 1
    g1r[0][lane]     = gib[lane];
    g1r[0][64+lane]  = gib[64+lane];
    g1r[0][128+lane] = gib[128+lane];
    giv0 = gib[192 + lane];
    giv1 = gib[192 + 64+lane];
    giv2 = gib[192 + 128+lane];
  }
  if(tid < 64){ h1s[tid]=0.f; h2s[tid]=0.f; }
  __syncthreads();

  const float4* hq = (const float4*)((w==2) ? h2s : h1s);

  for(int i=0;i<=TT;i++){
    // ---- phase A ----
    if(w == 0){
      int pst = i+1;
      if(pst < TT){
        g1r[pst&1][lane]     = giv0;
        g1r[pst&1][64+lane]  = giv1;
        g1r[pst&1][128+lane] = giv2;
      }
      int nst = i+2;
      if(nst < TT){
        giv0 = gib[(size_t)nst*192 + lane];
        giv1 = gib[(size_t)nst*192 + 64+lane];
        giv2 = gib[(size_t)nst*192 + 128+lane];
      }
    }
    // uniform (broadcast) h reads: 16 independent ds_read_b128, no SGPR hazards
    float4 q0=hq[0],  q1=hq[1],  q2=hq[2],  q3=hq[3];
    float4 q4=hq[4],  q5=hq[5],  q6=hq[6],  q7=hq[7];
    float4 q8=hq[8],  q9=hq[9],  qA=hq[10], qB=hq[11];
    float4 qC=hq[12], qD=hq[13], qE=hq[14], qF=hq[15];
    float a0=biasA, a1=0.f, a2=0.f, a3=0.f;
    float b0=biasB, b1_=0.f, b2_=0.f, b3=0.f;
    float c0=biasC, c1=0.f, c2=0.f, c3=0.f;
#define DOT4(WA, WB, WC, HQ) { \
    a0 = fmaf(HQ.x, WA.x, a0);  b0  = fmaf(HQ.x, WB.x, b0);  c0 = fmaf(HQ.x, WC.x, c0); \
    a1 = fmaf(HQ.y, WA.y, a1);  b1_ = fmaf(HQ.y, WB.y, b1_); c1 = fmaf(HQ.y, WC.y, c1); \
    a2 = fmaf(HQ.z, WA.z, a2);  b2_ = fmaf(HQ.z, WB.z, b2_); c2 = fmaf(HQ.z, WC.z, c2); \
    a3 = fmaf(HQ.w, WA.w, a3);  b3  = fmaf(HQ.w, WB.w, b3);  c3 = fmaf(HQ.w, WC.w, c3); }
    DOT4(Av0,Bv0,Cv0, q0)  DOT4(Av1,Bv1,Cv1, q1)  DOT4(Av2,Bv2,Cv2, q2)  DOT4(Av3,Bv3,Cv3, q3)
    DOT4(Av4,Bv4,Cv4, q4)  DOT4(Av5,Bv5,Cv5, q5)  DOT4(Av6,Bv6,Cv6, q6)  DOT4(Av7,Bv7,Cv7, q7)
    DOT4(Av8,Bv8,Cv8, q8)  DOT4(Av9,Bv9,Cv9, q9)  DOT4(AvA,BvA,CvA, qA)  DOT4(AvB,BvB,CvB, qB)
    DOT4(AvC,BvC,CvC, qC)  DOT4(AvD,BvD,CvD, qD)  DOT4(AvE,BvE,CvE, qE)  DOT4(AvF,BvF,CvF, qF)
#undef DOT4
    dst[lane]     = (a0+a1)+(a2+a3);
    dst[64+lane]  = (b0+b1_)+(b2_+b3);
    dst[128+lane] = (c0+c1)+(c2+c3);
    __syncthreads();
    // ---- phase B: gate updates (guards define the skew) ----
    if(w == 0){
      if(i < TT){
        float r = sigmf(g1r[i&1][lane]     + gh1s[lane]);
        float z = sigmf(g1r[i&1][64+lane]  + gh1s[64+lane]);
        float n = tanhfast(g1r[i&1][128+lane] + r*gh1s[128+lane]);
        h1s[lane] = (1.f-z)*n + z*h1s[lane];
      }
    } else if(w == 2){
      if(i >= 1){
        float r = sigmf(gi2s[lane]     + gh2s[lane]);
        float z = sigmf(gi2s[64+lane]  + gh2s[64+lane]);
        float n = tanhfast(gi2s[128+lane] + r*gh2s[128+lane]);
        h2s[lane] = (1.f-z)*n + z*h2s[lane];
      }
    }
    __syncthreads();
  }

  if(tid < 24){
    float acc = bl[tid];
    const float4* wl4 = (const float4*)(Wl + tid*64);
    #pragma unroll
    for(int k4=0;k4<16;k4++){
      float4 h4 = *(const float4*)(h2s + 4*k4);
      float4 w4 = wl4[k4];
      acc += h4.x*w4.x + h4.y*w4.y + h4.z*w4.z + h4.w*w4.w;
    }
    fout[b*24+tid] = acc;
  }
}

extern "C" void kernel_launch(void* const* d_in, const int* in_sizes, int n_in,
                              void* d_out, int out_size, void* d_ws, size_t ws_size,
                              hipStream_t stream){
  const float* x     =(const float*)d_in[0];
  const int*   ei    =(const int*  )d_in[1];
  const float* W1    =(const float*)d_in[3];
  const float* a_src1=(const float*)d_in[4];
  const float* a_dst1=(const float*)d_in[5];
  const float* b1    =(const float*)d_in[6];
  const float* W2    =(const float*)d_in[7];
  const float* a_src2=(const float*)d_in[8];
  const float* a_dst2=(const float*)d_in[9];
  const float* b2    =(const float*)d_in[10];
  const float* Wih0  =(const float*)d_in[11];
  const float* Whh0  =(const float*)d_in[12];
  const float* bih0  =(const float*)d_in[13];
  const float* bhh0  =(const float*)d_in[14];
  const float* Wih1  =(const float*)d_in[15];
  const float* Whh1  =(const float*)d_in[16];
  const float* bih1  =(const float*)d_in[17];
  const float* bhh1  =(const float*)d_in[18];
  const float* Wl    =(const float*)d_in[19];
  const float* bl    =(const float*)d_in[20];

  float* ws   = (float*)d_ws;
  float* agg  = ws;                  // 4194304 [N,128] (dead after k_g12)
  float* s14  = ws + 4194304;        // 131072 [N,4]
  float* gi   = ws;                  // overwrites agg after it's dead
  float* out2 = ws + 8388608;        // 2097152 (k_gat2 output)
  float* h2   = ws + 16777216;       // 2097152
  float* as1  = ws + 18874368;       // 131072
  float* ad1  = as1 + 131072;        // 131072
  float* as2  = ad1 + 131072;        // 32768
  float* ad2  = as2 + 32768;         // 32768
  int* rowptr = (int*)(ad2 + 32768); // 32769 (padded to 32800)
  int* deg    = rowptr + 32800;      // 32768
  int* cur    = deg + 32768;         // 32768 (contiguous with deg: one memset)
  int* col    = cur + 32768;         // 557056
  float* fo   = (float*)d_out;

  hipMemsetAsync(deg, 0, 2*32768*sizeof(int), stream);  // deg + cur

  k_deg   <<<2176,256,0,stream>>>(ei,deg);
  k_scan  <<<1  ,1024,0,stream>>>(deg,rowptr);
  k_fill  <<<2176,256,0,stream>>>(ei,rowptr,cur,col);

  k_alpha1x<<<128 ,256,0,stream>>>(x,W1,a_src1,a_dst1,as1,ad1);
  k_gatx   <<<8192,256,0,stream>>>(rowptr,col,as1,ad1,x,agg,s14);
  k_g12    <<<1024,256,0,stream>>>(agg,W1,s14,b1,W2,a_src2,a_dst2,h2,as2,ad2);
  k_gat2   <<<8192,256,0,stream>>>(rowptr,col,as2,ad2,h2,b2,out2);
  k_gemm_gi<<<512 ,256,0,stream>>>(out2,Wih0,bih0,bhh0,gi);
  k_gru3   <<<64  ,192,0,stream>>>(gi,Whh0,bhh0,Wih1,bih1,Whh1,bhh1,Wl,bl,fo);
  (void)in_sizes; (void)n_in; (void)out_size; (void)ws_size;
}

// Round 10
// 732.325 us; speedup vs baseline: 1.3756x; 1.2673x over previous
//
#include <hip/hip_runtime.h>
#include <hip/hip_bf16.h>

#define N_NODES 32768
#define F_IN    32
#define HC      64
#define HEADS   4
#define NE      524288
#define NET     (NE + N_NODES)   /* 557056 = 2176*256 */
#define NG      64
#define TT      512
#define OUTF    24

__device__ __forceinline__ float lrelu(float x){ return x > 0.f ? x : 0.2f*x; }
__device__ __forceinline__ float eluf (float x){ return x > 0.f ? x : __expf(x)-1.f; }
__device__ __forceinline__ float sigmf(float x){ return 1.f/(1.f+__expf(-x)); }
__device__ __forceinline__ float tanhfast(float x){ return 1.f - 2.f/(__expf(2.f*x)+1.f); }
__device__ __forceinline__ float bcast(float v, int k){
  return __int_as_float(__builtin_amdgcn_readlane(__float_as_int(v), k));
}

// ---------------- CSR build: incoming-edge lists per destination ----------------
__global__ __launch_bounds__(256) void k_deg(const int* __restrict__ ei,
                                             int* __restrict__ deg){
  int e = blockIdx.x*256 + threadIdx.x;   // e < NET
  int d = (e < NE) ? ei[NE+e] : (e - NE);
  atomicAdd(deg + d, 1);
}

__global__ __launch_bounds__(1024) void k_scan(const int* __restrict__ deg,
                                               int* __restrict__ rowptr){
  __shared__ int ps[1024];
  const int t = threadIdx.x;
  const int base = t*32;
  int local[32]; int s = 0;
  #pragma unroll
  for(int i=0;i<32;i++){ local[i]=deg[base+i]; s+=local[i]; }
  ps[t]=s; __syncthreads();
  for(int off=1; off<1024; off<<=1){
    int v = (t>=off) ? ps[t-off] : 0;
    __syncthreads();
    ps[t]+=v;
    __syncthreads();
  }
  int run = (t==0) ? 0 : ps[t-1];
  #pragma unroll
  for(int i=0;i<32;i++){ rowptr[base+i]=run; run+=local[i]; }
  if(t==1023) rowptr[N_NODES]=run;
}

__global__ __launch_bounds__(256) void k_fill(const int* __restrict__ ei,
                                              const int* __restrict__ rowptr,
                                              int* __restrict__ cur,
                                              int* __restrict__ col){
  int e = blockIdx.x*256 + threadIdx.x;   // e < NET
  int s, d;
  if(e < NE){ s = ei[e]; d = ei[NE+e]; } else { s = e-NE; d = s; }
  int pos = atomicAdd(cur + d, 1);
  col[rowptr[d] + pos] = s;
}

// ---------------- GAT layer 1, restructured (h1 never materialized) ----------------
__global__ __launch_bounds__(256) void k_alpha1x(const float* __restrict__ x,
                                                 const float* __restrict__ W1,
                                                 const float* __restrict__ a_src,
                                                 const float* __restrict__ a_dst,
                                                 float* __restrict__ as1,
                                                 float* __restrict__ ad1){
  __shared__ float ps[256];
  const int tid = threadIdx.x;
  {
    const int k = tid>>3, q = tid&7;
    const int h = q>>1, isd = q&1;
    const float* av = (isd ? a_dst : a_src) + h*64;
    const float* wr = W1 + k*256 + h*64;
    float acc = 0.f;
    #pragma unroll
    for(int c=0;c<64;c++) acc += wr[c]*av[c];
    ps[(isd?128:0) + k*4 + h] = acc;
  }
  __syncthreads();
  const int n = blockIdx.x*256 + tid;
  const float4* xr = (const float4*)(x + n*32);
  float sa0=0.f,sa1=0.f,sa2=0.f,sa3=0.f, sd0=0.f,sd1=0.f,sd2=0.f,sd3=0.f;
  #pragma unroll
  for(int k4=0;k4<8;k4++){
    float4 v = xr[k4];
    const float* pa = ps + (4*k4)*4;
    const float* pd = ps + 128 + (4*k4)*4;
    sa0 += v.x*pa[0] + v.y*pa[4] + v.z*pa[8]  + v.w*pa[12];
    sa1 += v.x*pa[1] + v.y*pa[5] + v.z*pa[9]  + v.w*pa[13];
    sa2 += v.x*pa[2] + v.y*pa[6] + v.z*pa[10] + v.w*pa[14];
    sa3 += v.x*pa[3] + v.y*pa[7] + v.z*pa[11] + v.w*pa[15];
    sd0 += v.x*pd[0] + v.y*pd[4] + v.z*pd[8]  + v.w*pd[12];
    sd1 += v.x*pd[1] + v.y*pd[5] + v.z*pd[9]  + v.w*pd[13];
    sd2 += v.x*pd[2] + v.y*pd[6] + v.z*pd[10] + v.w*pd[14];
    sd3 += v.x*pd[3] + v.y*pd[7] + v.z*pd[11] + v.w*pd[15];
  }
  *(float4*)(as1+n*4) = make_float4(sa0,sa1,sa2,sa3);
  *(float4*)(ad1+n*4) = make_float4(sd0,sd1,sd2,sd3);
}

// aggregate x per (node, head): agg[d,h,k] = sum_e w_e^h x[src_e,k]; s14 = sum w.
__global__ __launch_bounds__(256) void k_gatx(const int* __restrict__ rowptr,
                                              const int* __restrict__ col,
                                              const float* __restrict__ as1,
                                              const float* __restrict__ ad1,
                                              const float* __restrict__ x,
                                              float* __restrict__ agg,
                                              float* __restrict__ s14){
  const int node = blockIdx.x*4 + (threadIdx.x>>6);
  const int lane = threadIdx.x & 63;
  const int h0   = lane>>5;                  // 0 or 1
  const int c    = lane & 31;
  const int beg = rowptr[node], end = rowptr[node+1];
  const float adA = ad1[node*4 + h0];
  const float adB = ad1[node*4 + h0 + 2];
  float accA=0.f, accB=0.f, wsA=0.f, wsB=0.f;
  int j = beg;
  for(; j+3 < end; j += 4){
    int s0 = col[j], s1 = col[j+1], s2 = col[j+2], s3 = col[j+3];
    float4 q0 = *(const float4*)(as1 + s0*4);
    float4 q1 = *(const float4*)(as1 + s1*4);
    float4 q2 = *(const float4*)(as1 + s2*4);
    float4 q3 = *(const float4*)(as1 + s3*4);
    float x0 = x[s0*32 + c];
    float x1 = x[s1*32 + c];
    float x2 = x[s2*32 + c];
    float x3 = x[s3*32 + c];
    float wA0 = __expf(lrelu((h0?q0.y:q0.x) + adA));
    float wA1 = __expf(lrelu((h0?q1.y:q1.x) + adA));
    float wA2 = __expf(lrelu((h0?q2.y:q2.x) + adA));
    float wA3 = __expf(lrelu((h0?q3.y:q3.x) + adA));
    float wB0 = __expf(lrelu((h0?q0.w:q0.z) + adB));
    float wB1 = __expf(lrelu((h0?q1.w:q1.z) + adB));
    float wB2 = __expf(lrelu((h0?q2.w:q2.z) + adB));
    float wB3 = __expf(lrelu((h0?q3.w:q3.z) + adB));
    accA += wA0*x0 + wA1*x1 + wA2*x2 + wA3*x3;
    accB += wB0*x0 + wB1*x1 + wB2*x2 + wB3*x3;
    wsA  += (wA0+wA1) + (wA2+wA3);
    wsB  += (wB0+wB1) + (wB2+wB3);
  }
  for(; j < end; j++){
    int s0 = col[j];
    float4 q0 = *(const float4*)(as1 + s0*4);
    float wA0 = __expf(lrelu((h0?q0.y:q0.x) + adA));
    float wB0 = __expf(lrelu((h0?q0.w:q0.z) + adB));
    float x0 = x[s0*32 + c];
    accA += wA0*x0; accB += wB0*x0;
    wsA += wA0; wsB += wB0;
  }
  agg[node*128 + h0*32 + c]     = accA;
  agg[node*128 + (h0+2)*32 + c] = accB;
  if(c == 0){
    s14[node*4 + h0]     = wsA;
    s14[node*4 + h0 + 2] = wsB;
  }
}

// Fused: out1 = ELU(agg@W1/s + b1) [LDS only] ; h2 = out1@W2 ; as2/ad2 from h2.
__global__ __launch_bounds__(256) void k_g12(const float* __restrict__ agg,
                                             const float* __restrict__ W1,
                                             const float* __restrict__ s14,
                                             const float* __restrict__ b1,
                                             const float* __restrict__ W2,
                                             const float* __restrict__ a_src2,
                                             const float* __restrict__ a_dst2,
                                             float* __restrict__ h2,
                                             float* __restrict__ as2,
                                             float* __restrict__ ad2){
  __shared__ __align__(16) float ags[32*128];   // 16KB; reused as h2 tile
  __shared__ __align__(16) float o1s[32*256];   // 32KB
  __shared__ float sv[128];
  const int tid  = threadIdx.x;
  const int row0 = blockIdx.x*32;
  const float4* ag = (const float4*)(agg + (size_t)row0*128);
  float4* a4 = (float4*)ags;
  for(int i=tid;i<1024;i+=256) a4[i]=ag[i];
  if(tid<32) ((float4*)sv)[tid]=((const float4*)(s14+row0*4))[tid];
  float wc[32];
  #pragma unroll
  for(int k=0;k<32;k++) wc[k]=W1[k*256+tid];
  const float bb=b1[tid];
  __syncthreads();
  const int h = tid>>6;
  for(int r=0;r<32;r++){
    const float4* ar=(const float4*)(ags + r*128 + h*32);
    float acc=0.f;
    #pragma unroll
    for(int k4=0;k4<8;k4++){
      float4 v=ar[k4];
      acc += v.x*wc[4*k4]+v.y*wc[4*k4+1]+v.z*wc[4*k4+2]+v.w*wc[4*k4+3];
    }
    float inv = 1.f/(sv[r*4+h] + 1e-16f);
    o1s[r*256+tid] = eluf(acc*inv + bb);
  }
  __syncthreads();
  const int c0=(tid&15)*4;
  const int r0=(tid>>4)*2;
  float acc2[2][4]={};
  for(int k=0;k<256;k+=4){
    float wv[4][4];
    #pragma unroll
    for(int i=0;i<4;i++){
      float4 w=*(const float4*)(W2+(k+i)*64+c0);
      wv[i][0]=w.x; wv[i][1]=w.y; wv[i][2]=w.z; wv[i][3]=w.w;
    }
    #pragma unroll
    for(int i=0;i<2;i++){
      float4 xv=*(const float4*)(o1s+(r0+i)*256+k);
      #pragma unroll
      for(int j=0;j<4;j++)
        acc2[i][j]+=xv.x*wv[0][j]+xv.y*wv[1][j]+xv.z*wv[2][j]+xv.w*wv[3][j];
    }
  }
  float* h2s = ags;
  #pragma unroll
  for(int i=0;i<2;i++){
    float4 o = make_float4(acc2[i][0],acc2[i][1],acc2[i][2],acc2[i][3]);
    *(float4*)(h2 + (size_t)(row0+r0+i)*64 + c0) = o;
    *(float4*)(h2s + (r0+i)*64 + c0) = o;
  }
  __syncthreads();
  if(tid < 32){
    const float4* hp=(const float4*)(h2s + tid*64);
    float sa=0.f, sd=0.f;
    #pragma unroll
    for(int i=0;i<16;i++){
      float4 v=hp[i];
      float4 a=((const float4*)a_src2)[i];
      float4 d=((const float4*)a_dst2)[i];
      sa+=v.x*a.x+v.y*a.y+v.z*a.z+v.w*a.w;
      sd+=v.x*d.x+v.y*d.y+v.z*d.z+v.w*d.w;
    }
    as2[row0+tid]=sa; ad2[row0+tid]=sd;
  }
}

// fused gather layer 2: one wave per node, lane = channel; 4-wide unrolled.
__global__ __launch_bounds__(256) void k_gat2(const int* __restrict__ rowptr,
                                              const int* __restrict__ col,
                                              const float* __restrict__ as2,
                                              const float* __restrict__ ad2,
                                              const float* __restrict__ h2,
                                              const float* __restrict__ b2,
                                              float* __restrict__ out2){
  const int node = blockIdx.x*4 + (threadIdx.x>>6);
  const int lane = threadIdx.x & 63;
  const int beg = rowptr[node], end = rowptr[node+1];
  const float ad = ad2[node];
  float acc = 0.f, s = 0.f;
  int j = beg;
  for(; j+3 < end; j += 4){
    int s0 = col[j], s1 = col[j+1], s2 = col[j+2], s3 = col[j+3];
    float a0 = as2[s0], a1 = as2[s1], a2 = as2[s2], a3 = as2[s3];
    float v0 = h2[s0*64+lane], v1 = h2[s1*64+lane];
    float v2 = h2[s2*64+lane], v3 = h2[s3*64+lane];
    float w0 = __expf(lrelu(a0 + ad));
    float w1 = __expf(lrelu(a1 + ad));
    float w2 = __expf(lrelu(a2 + ad));
    float w3 = __expf(lrelu(a3 + ad));
    acc += w0*v0 + w1*v1 + w2*v2 + w3*v3;
    s += (w0+w1) + (w2+w3);
  }
  for(; j < end; j++){
    int s0 = col[j];
    float w0 = __expf(lrelu(as2[s0] + ad));
    acc += w0*h2[s0*64+lane];
    s += w0;
  }
  const float inv = 1.f/(s + 1e-16f);
  out2[node*64+lane] = eluf(acc*inv + b2[lane]);
}

// ---------------- GRU: gi1 = in @ Wih0^T + bih0   [N,64]@[64,192] ----------------
__global__ __launch_bounds__(256) void k_gemm_gi(const float* __restrict__ in,
                                                 const float* __restrict__ Wih,
                                                 const float* __restrict__ bih,
                                                 float* __restrict__ gi){
  __shared__ __align__(16) float xs[64*64];
  __shared__ float wT[64*192];
  const int tid=threadIdx.x;
  const int row0=blockIdx.x*64;
  const float4* xg=(const float4*)(in+row0*64);
  float4* xs4=(float4*)xs;
  for(int i=tid;i<1024;i+=256) xs4[i]=xg[i];
  for(int i=tid;i<12288;i+=256){ wT[(i&63)*192+(i>>6)] = Wih[i]; }
  __syncthreads();
  if(tid<192){
    float wr[64];
    #pragma unroll
    for(int k=0;k<64;k++) wr[k]=wT[k*192+tid];
    const float bj=bih[tid];
    for(int r=0;r<64;r++){
      float acc=bj;
      const float4* xr=(const float4*)(xs+r*64);
      #pragma unroll
      for(int k4=0;k4<16;k4++){
        float4 v=xr[k4];
        acc+=v.x*wr[4*k4]+v.y*wr[4*k4+1]+v.z*wr[4*k4+2]+v.w*wr[4*k4+3];
      }
      gi[(row0+r)*192+tid]=acc;
    }
  }
}

// Fused 2-layer GRU, 3 waves, register-resident recurrences, 1 barrier/step.
// r8 insight: wave0's gate inputs gh1[lane],[64+lane],[128+lane] are its OWN
// matvec outputs (rows lane/64+lane/128+lane) — already in registers. Same for
// wave2's gh2. So h1 and h2 recurrences never need the LDS round-trip or the
// 2-barrier phase structure of the r0 kernel. Only two LAGGED cross-wave
// handoffs exist: h1 -> wave1 (computes gi2 one step behind) and gi2 -> wave2
// (gates one further step behind). Both get a full step of slack via 2-slot
// LDS rings + ONE barrier per iteration. Readlane broadcasts (r7 proved LDS
// broadcast costs ~576 cyc/step through the shared LDS pipe; readlane is the
// cheap path). Math byte-identical to the verified r0 kernel (absmax=0).
// Schedule: iter i: wave0 computes h1 step i (i<TT); wave1 computes
// gi2[i-1] from h1ring (1<=i<=TT); wave2 gates h2 with gi2[i-2] (i>=2).
// 514 iterations total. Barriers are uniform (act guards compute only);
// all global accesses bounds-checked (r9 audit: resubmitted after infra
// failure, no kernel change).
__global__ __launch_bounds__(192,1) void k_gru3r(const float* __restrict__ gi1,
                                                 const float* __restrict__ Whh0,
                                                 const float* __restrict__ bhh0,
                                                 const float* __restrict__ Wih1,
                                                 const float* __restrict__ bih1,
                                                 const float* __restrict__ Whh1,
                                                 const float* __restrict__ bhh1,
                                                 const float* __restrict__ Wl,
                                                 const float* __restrict__ bl,
                                                 float* __restrict__ fout){
  __shared__ float h1ring[2][64];
  __shared__ float gi2ring[2][192];
  __shared__ float h2fin[64];
  const int tid  = threadIdx.x;
  const int w    = tid >> 6;
  const int lane = tid & 63;
  const int b    = blockIdx.x;
  const float* gib = gi1 + (size_t)b*TT*192;

  const float* W  = (w==0) ? Whh0 : (w==1) ? Wih1 : Whh1;
  const float* bb = (w==0) ? bhh0 : (w==1) ? bih1 : bhh1;

  const float4* pa = (const float4*)(W + lane*64);
  const float4* pb = (const float4*)(W + (64+lane)*64);
  const float4* pc = (const float4*)(W + (128+lane)*64);
  float4 Av0=pa[0],  Av1=pa[1],  Av2=pa[2],  Av3=pa[3];
  float4 Av4=pa[4],  Av5=pa[5],  Av6=pa[6],  Av7=pa[7];
  float4 Av8=pa[8],  Av9=pa[9],  AvA=pa[10], AvB=pa[11];
  float4 AvC=pa[12], AvD=pa[13], AvE=pa[14], AvF=pa[15];
  float4 Bv0=pb[0],  Bv1=pb[1],  Bv2=pb[2],  Bv3=pb[3];
  float4 Bv4=pb[4],  Bv5=pb[5],  Bv6=pb[6],  Bv7=pb[7];
  float4 Bv8=pb[8],  Bv9=pb[9],  BvA=pb[10], BvB=pb[11];
  float4 BvC=pb[12], BvD=pb[13], BvE=pb[14], BvF=pb[15];
  float4 Cv0=pc[0],  Cv1=pc[1],  Cv2=pc[2],  Cv3=pc[3];
  float4 Cv4=pc[4],  Cv5=pc[5],  Cv6=pc[6],  Cv7=pc[7];
  float4 Cv8=pc[8],  Cv9=pc[9],  CvA=pc[10], CvB=pc[11];
  float4 CvC=pc[12], CvD=pc[13], CvE=pc[14], CvF=pc[15];
  const float biasA = bb[lane];
  const float biasB = bb[64+lane];
  const float biasC = bb[128+lane];

  // wave0 gi1 registers: cur = step 0, nxt = step 1
  float gc0=0.f,gc1=0.f,gc2=0.f, gn0=0.f,gn1=0.f,gn2=0.f;
  if(w == 0){
    gc0 = gib[lane];       gc1 = gib[64+lane];       gc2 = gib[128+lane];
    gn0 = gib[192+lane];   gn1 = gib[192+64+lane];   gn2 = gib[192+128+lane];
  }
  float h = 0.f;   // wave0: h1 ; wave2: h2 ; wave1: unused
  __syncthreads();

  for(int i=0;i<=TT+1;i++){
    const bool act = (w==0) ? (i < TT) : (w==1) ? (i >= 1 && i <= TT) : (i >= 2);
    // broadcast source
    float hv = h;
    if(w == 1 && act) hv = h1ring[(i-1)&1][lane];
    // wave2: issue gi2 ring reads early (written iter i-1, barrier passed)
    float gv0=0.f, gv1=0.f, gv2=0.f;
    if(w == 2 && act){
      gv0 = gi2ring[(i-1)&1][lane];
      gv1 = gi2ring[(i-1)&1][64+lane];
      gv2 = gi2ring[(i-1)&1][128+lane];
    }
    // wave0: prefetch gi1 step i+2
    float f0=0.f, f1=0.f, f2=0.f;
    if(w == 0 && i+2 < TT){
      const float* g2 = gib + (size_t)(i+2)*192;
      f0 = g2[lane]; f1 = g2[64+lane]; f2 = g2[128+lane];
    }
    if(act){
      float a0=biasA, a1=0.f, a2=0.f, a3=0.f;
      float b0=biasB, b1_=0.f, b2_=0.f, b3=0.f;
      float c0=biasC, c1=0.f, c2=0.f, c3=0.f;
#define DOT4(WA, WB, WC, BASE) { \
      float t0=bcast(hv,BASE+0), t1=bcast(hv,BASE+1), t2=bcast(hv,BASE+2), t3=bcast(hv,BASE+3); \
      a0 = fmaf(t0, WA.x, a0);  b0  = fmaf(t0, WB.x, b0);  c0 = fmaf(t0, WC.x, c0); \
      a1 = fmaf(t1, WA.y, a1);  b1_ = fmaf(t1, WB.y, b1_); c1 = fmaf(t1, WC.y, c1); \
      a2 = fmaf(t2, WA.z, a2);  b2_ = fmaf(t2, WB.z, b2_); c2 = fmaf(t2, WC.z, c2); \
      a3 = fmaf(t3, WA.w, a3);  b3  = fmaf(t3, WB.w, b3);  c3 = fmaf(t3, WC.w, c3); }
      DOT4(Av0,Bv0,Cv0, 0)  DOT4(Av1,Bv1,Cv1, 4)  DOT4(Av2,Bv2,Cv2, 8)  DOT4(Av3,Bv3,Cv3, 12)
      DOT4(Av4,Bv4,Cv4, 16) DOT4(Av5,Bv5,Cv5, 20) DOT4(Av6,Bv6,Cv6, 24) DOT4(Av7,Bv7,Cv7, 28)
      DOT4(Av8,Bv8,Cv8, 32) DOT4(Av9,Bv9,Cv9, 36) DOT4(AvA,BvA,CvA, 40) DOT4(AvB,BvB,CvB, 44)
      DOT4(AvC,BvC,CvC, 48) DOT4(AvD,BvD,CvD, 52) DOT4(AvE,BvE,CvE, 56) DOT4(AvF,BvF,CvF, 60)
#undef DOT4
      float ghA = (a0+a1)+(a2+a3);
      float ghB = (b0+b1_)+(b2_+b3);
      float ghC = (c0+c1)+(c2+c3);
      if(w == 0){
        float r = sigmf(gc0 + ghA);
        float z = sigmf(gc1 + ghB);
        float n = tanhfast(gc2 + r*ghC);
        h = (1.f-z)*n + z*h;
        h1ring[i&1][lane] = h;
        gc0 = gn0; gc1 = gn1; gc2 = gn2;
        gn0 = f0;  gn1 = f1;  gn2 = f2;
      } else if(w == 1){
        gi2ring[i&1][lane]     = ghA;
        gi2ring[i&1][64+lane]  = ghB;
        gi2ring[i&1][128+lane] = ghC;
      } else {
        float r = sigmf(gv0 + ghA);
        float z = sigmf(gv1 + ghB);
        float n = tanhfast(gv2 + r*ghC);
        h = (1.f-z)*n + z*h;
      }
    }
    __syncthreads();
  }

  if(w == 2) h2fin[lane] = h;
  __syncthreads();
  if(tid < 24){
    float acc = bl[tid];
    const float4* wl4 = (const float4*)(Wl + tid*64);
    #pragma unroll
    for(int k4=0;k4<16;k4++){
      float4 h4 = *(const float4*)(h2fin + 4*k4);
      float4 w4 = wl4[k4];
      acc += h4.x*w4.x + h4.y*w4.y + h4.z*w4.z + h4.w*w4.w;
    }
    fout[b*24+tid] = acc;
  }
}

extern "C" void kernel_launch(void* const* d_in, const int* in_sizes, int n_in,
                              void* d_out, int out_size, void* d_ws, size_t ws_size,
                              hipStream_t stream){
  const float* x     =(const float*)d_in[0];
  const int*   ei    =(const int*  )d_in[1];
  const float* W1    =(const float*)d_in[3];
  const float* a_src1=(const float*)d_in[4];
  const float* a_dst1=(const float*)d_in[5];
  const float* b1    =(const float*)d_in[6];
  const float* W2    =(const float*)d_in[7];
  const float* a_src2=(const float*)d_in[8];
  const float* a_dst2=(const float*)d_in[9];
  const float* b2    =(const float*)d_in[10];
  const float* Wih0  =(const float*)d_in[11];
  const float* Whh0  =(const float*)d_in[12];
  const float* bih0  =(const float*)d_in[13];
  const float* bhh0  =(const float*)d_in[14];
  const float* Wih1  =(const float*)d_in[15];
  const float* Whh1  =(const float*)d_in[16];
  const float* bih1  =(const float*)d_in[17];
  const float* bhh1  =(const float*)d_in[18];
  const float* Wl    =(const float*)d_in[19];
  const float* bl    =(const float*)d_in[20];

  float* ws   = (float*)d_ws;
  float* agg  = ws;                  // 4194304 [N,128] (dead after k_g12)
  float* s14  = ws + 4194304;        // 131072 [N,4]
  float* gi   = ws;                  // overwrites agg after it's dead
  float* out2 = ws + 8388608;        // 2097152 (k_gat2 output)
  float* h2   = ws + 16777216;       // 2097152
  float* as1  = ws + 18874368;       // 131072
  float* ad1  = as1 + 131072;        // 131072
  float* as2  = ad1 + 131072;        // 32768
  float* ad2  = as2 + 32768;         // 32768
  int* rowptr = (int*)(ad2 + 32768); // 32769 (padded to 32800)
  int* deg    = rowptr + 32800;      // 32768
  int* cur    = deg + 32768;         // 32768 (contiguous with deg: one memset)
  int* col    = cur + 32768;         // 557056
  float* fo   = (float*)d_out;

  hipMemsetAsync(deg, 0, 2*32768*sizeof(int), stream);  // deg + cur

  k_deg   <<<2176,256,0,stream>>>(ei,deg);
  k_scan  <<<1  ,1024,0,stream>>>(deg,rowptr);
  k_fill  <<<2176,256,0,stream>>>(ei,rowptr,cur,col);

  k_alpha1x<<<128 ,256,0,stream>>>(x,W1,a_src1,a_dst1,as1,ad1);
  k_gatx   <<<8192,256,0,stream>>>(rowptr,col,as1,ad1,x,agg,s14);
  k_g12    <<<1024,256,0,stream>>>(agg,W1,s14,b1,W2,a_src2,a_dst2,h2,as2,ad2);
  k_gat2   <<<8192,256,0,stream>>>(rowptr,col,as2,ad2,h2,b2,out2);
  k_gemm_gi<<<512 ,256,0,stream>>>(out2,Wih0,bih0,gi);
  k_gru3r  <<<64  ,192,0,stream>>>(gi,Whh0,bhh0,Wih1,bih1,Whh1,bhh1,Wl,bl,fo);
  (void)in_sizes; (void)n_in; (void)out_size; (void)ws_size;
}